// Round 21
// baseline (67.302 us; speedup 1.0000x reference)
//
#include <hip/hip_runtime.h>
#include <hip/hip_bf16.h>

typedef __attribute__((ext_vector_type(8))) short bf16x8;
typedef __attribute__((ext_vector_type(4))) float f32x4;

#define D_DIM 256   // input feature dim
#define H_DIM 128   // hidden dim per branch
#define QSH 12544   // rows per quarter; LDS f32 acc = 50176 B
#define NSL 64      // edge slices (k2q grid = NSL*4 = 256 blocks, 1/CU)
#define NMAXL (4 * QSH)   // max N for lds path (=> 100352 B bf16 dis LDS)

// RNE float->bf16 (bit pattern)
__device__ inline ushort f2bf(float f) {
    union { float f; unsigned u; } a; a.f = f;
    unsigned r = a.u + 0x7fffu + ((a.u >> 16) & 1u);
    return (ushort)(r >> 16);
}
__device__ inline float bf2f(unsigned hi16) {
    union { unsigned u; float f; } a; a.u = hi16 << 16;
    return a.f;
}

// K0: (a) xbf: x converted to bf16 in MFMA-A-FRAGMENT order:
//     xbf[((T16*8 + ks)*64 + l)*8 + e] = x[T16*16 + (l&15)][ks*32 + (l>>4)*8 + e]
//     (thread = input position: coalesced 32B reads, scattered 16B writes)
//     (b) Wt: row-major bf16 [hcat][k]; (c) dis init for fallback.
__global__ void k0_init(const float* __restrict__ x,
                        const float* __restrict__ W_nb, const float* __restrict__ W_self,
                        ushort* __restrict__ Wt, ushort* __restrict__ xbf,
                        float* __restrict__ dis, int N, int init_dis, int do_xbf) {
    int i = blockIdx.x * 256 + threadIdx.x;
    if (do_xbf && i < N * 32) {
        int n     = i >> 5;
        int kbase = (i & 31) * 8;
        const float4* s = reinterpret_cast<const float4*>(x + (size_t)n * D_DIM + kbase);
        float4 a = s[0], b = s[1];
        uint4 o;
        o.x = (unsigned)f2bf(a.x) | ((unsigned)f2bf(a.y) << 16);
        o.y = (unsigned)f2bf(a.z) | ((unsigned)f2bf(a.w) << 16);
        o.z = (unsigned)f2bf(b.x) | ((unsigned)f2bf(b.y) << 16);
        o.w = (unsigned)f2bf(b.z) | ((unsigned)f2bf(b.w) << 16);
        int T    = n >> 4;
        int ks   = (i >> 2) & 7;
        int l    = (i & 3) * 16 + (n & 15);
        size_t word = ((size_t)T * 8 + ks) * 64 + l;
        *reinterpret_cast<uint4*>(xbf + word * 8) = o;
    }
    if (i < 2 * H_DIM * D_DIM) {
        int sel = i >> 15;
        int r   = i & 32767;
        int k   = r >> 7;
        int h   = r & 127;
        const float* W = sel ? W_self : W_nb;
        Wt[(sel * H_DIM + h) * D_DIM + k] = f2bf(W[k * H_DIM + h]);
    }
    if (init_dis && i < N) dis[i] = 1e-10f;
}

// K1 (LDS-B): block = 256 thr (4 waves), cls = bid&1 selects branch (64KB B slice).
// Stage branch slice of Wt into LDS (XOR-swizzled chunks -> conflict-free b128).
// Per 32-row tile: 16 coalesced 1KB A-loads from xbf (no A-LDS, no stage barrier),
// ds_read B fragments, 32 MFMA/wave, tiny part[] combine. VGPR ~140 (no spill).
__global__ __launch_bounds__(256, 2) void k1_ldsb(
    const ushort* __restrict__ xbf, const ushort* __restrict__ Wt,
    const float* __restrict__ b_nb, const float* __restrict__ b_self,
    const float* __restrict__ W_att,
    float* __restrict__ g_nb, float* __restrict__ g_self,
    int N, int nt16, int nt32)
{
    __shared__ ushort Bl[128 * 256];      // 64 KB: branch slice, swizzled
    __shared__ float part[4][32];

    const int t    = threadIdx.x;
    const int lane = t & 63;
    const int w    = t >> 6;              // wave 0..3 -> 32 h-cols each
    const int li   = lane & 15;
    const int grp  = lane >> 4;
    const int cls  = blockIdx.x & 1;      // 0: nb branch, 1: self branch

    // ---- stage Wt branch slice -> LDS (swizzled) ----
    {
        const ushort* Wtg = Wt + (size_t)cls * H_DIM * D_DIM;
        for (int q = t; q < 4096; q += 256) {        // 4096 x 16B chunks
            int row = q >> 5, c = q & 31;
            uint4 v = *reinterpret_cast<const uint4*>(Wtg + row * 256 + c * 8);
            *reinterpret_cast<uint4*>(&Bl[row * 256 + ((c ^ (row & 31)) << 3)]) = v;
        }
    }

    float bias[2], aw[2];
    #pragma unroll
    for (int ni2 = 0; ni2 < 2; ni2++) {
        int hl = w * 32 + ni2 * 16 + li;             // 0..127 within branch
        bias[ni2] = cls ? b_self[hl] : b_nb[hl];
        aw[ni2]   = W_att[cls * H_DIM + hl];
    }
    __syncthreads();

    const int G  = gridDim.x >> 1;
    const int r0 = w * 32 + li;
    const int r1 = r0 + 16;

    for (int T = blockIdx.x >> 1; T < nt32; T += G) {
        // ---- A fragments: 16 coalesced 1KB loads, direct from xbf ----
        bf16x8 af[2][8];
        #pragma unroll
        for (int mi = 0; mi < 2; mi++) {
            int t16 = 2 * T + mi;
            if (t16 < nt16) {
                #pragma unroll
                for (int ks = 0; ks < 8; ks++)
                    af[mi][ks] = *reinterpret_cast<const bf16x8*>(
                        xbf + (((size_t)t16 * 8 + ks) * 64 + lane) * 8);
            } else {
                #pragma unroll
                for (int ks = 0; ks < 8; ks++) af[mi][ks] = bf16x8{0,0,0,0,0,0,0,0};
            }
        }

        // ---- MFMA: B from LDS (swizzled ds_read_b128) ----
        f32x4 acc[2][2];
        #pragma unroll
        for (int mi = 0; mi < 2; mi++)
            #pragma unroll
            for (int ni2 = 0; ni2 < 2; ni2++) acc[mi][ni2] = f32x4{0.f, 0.f, 0.f, 0.f};

        #pragma unroll
        for (int ks = 0; ks < 8; ks++) {
            int c = ks * 4 + grp;
            bf16x8 b0 = *reinterpret_cast<const bf16x8*>(&Bl[r0 * 256 + ((c ^ (r0 & 31)) << 3)]);
            bf16x8 b1 = *reinterpret_cast<const bf16x8*>(&Bl[r1 * 256 + ((c ^ (r1 & 31)) << 3)]);
            acc[0][0] = __builtin_amdgcn_mfma_f32_16x16x32_bf16(af[0][ks], b0, acc[0][0], 0, 0, 0);
            acc[1][0] = __builtin_amdgcn_mfma_f32_16x16x32_bf16(af[1][ks], b0, acc[1][0], 0, 0, 0);
            acc[0][1] = __builtin_amdgcn_mfma_f32_16x16x32_bf16(af[0][ks], b1, acc[0][1], 0, 0, 0);
            acc[1][1] = __builtin_amdgcn_mfma_f32_16x16x32_bf16(af[1][ks], b1, acc[1][1], 0, 0, 0);
        }

        // ---- epilogue: bias+relu+aw, shfl-reduce over li, part combine ----
        #pragma unroll
        for (int mi = 0; mi < 2; mi++)
            #pragma unroll
            for (int r4 = 0; r4 < 4; r4++) {
                float y0 = acc[mi][0][r4] + bias[0];
                float y1 = acc[mi][1][r4] + bias[1];
                y0 = y0 > 0.f ? y0 : 0.f;
                y1 = y1 > 0.f ? y1 : 0.f;
                float s = y0 * aw[0] + y1 * aw[1];
                #pragma unroll
                for (int m = 1; m < 16; m <<= 1) s += __shfl_xor(s, m);
                if (li == 0) part[w][mi * 16 + grp * 4 + r4] = s;
            }
        __syncthreads();
        if (t < 32) {
            float val = part[0][t] + part[1][t] + part[2][t] + part[3][t];
            int ng = T * 32 + t;
            if (ng < N) (cls ? g_self : g_nb)[ng] = val;
        }
        __syncthreads();
    }
}

// K1 fallback (f32 x, row-major Wt) — only when xbf doesn't fit.
__global__ __launch_bounds__(512, 2) void k1_gemm_f(
    const float* __restrict__ x, const ushort* __restrict__ Wt,
    const float* __restrict__ b_nb, const float* __restrict__ b_self,
    const float* __restrict__ W_att,
    float* __restrict__ g_nb, float* __restrict__ g_self, int N, int ntiles)
{
    __shared__ __align__(16) ushort A_lds[64][264];
    __shared__ float part[2][2][64];

    const int t    = threadIdx.x;
    const int lane = t & 63;
    const int w    = t >> 6;
    const int rh   = w >> 2;
    const int cg   = w & 3;
    const int br   = cg >> 1;
    const int ch   = cg & 1;
    const int li   = lane & 15;
    const int grp  = lane >> 4;

    float bias[4], aw[4];
    #pragma unroll
    for (int ni = 0; ni < 4; ni++) {
        int hh = ch * 64 + ni * 16 + li;
        bias[ni] = br ? b_self[hh] : b_nb[hh];
        aw[ni]   = W_att[br * H_DIM + hh];
    }

    bf16x8 Bf[4][8];
    #pragma unroll
    for (int ni = 0; ni < 4; ni++)
        #pragma unroll
        for (int ks = 0; ks < 8; ks++)
            Bf[ni][ks] = *reinterpret_cast<const bf16x8*>(
                Wt + (size_t)(cg * 64 + ni * 16 + li) * D_DIM + ks * 32 + grp * 8);

    const int sr = t >> 3;
    const int sc = t & 7;

    for (int rt = blockIdx.x; rt < ntiles; rt += gridDim.x) {
        const int row0 = rt * 64;
        __syncthreads();
        {
            const int gr = row0 + sr;
            const bool v = gr < N;
            const float4* src = reinterpret_cast<const float4*>(x + (size_t)gr * D_DIM);
            #pragma unroll
            for (int j = 0; j < 8; j++) {
                int c4 = sc + j * 8;
                ushort4 o;
                if (v) {
                    float4 f = src[c4];
                    o.x = f2bf(f.x); o.y = f2bf(f.y); o.z = f2bf(f.z); o.w = f2bf(f.w);
                } else { o.x = 0; o.y = 0; o.z = 0; o.w = 0; }
                *reinterpret_cast<ushort4*>(&A_lds[sr][c4 * 4]) = o;
            }
        }
        __syncthreads();

        f32x4 acc[2][4];
        #pragma unroll
        for (int mi = 0; mi < 2; mi++)
            #pragma unroll
            for (int ni = 0; ni < 4; ni++) acc[mi][ni] = f32x4{0.f, 0.f, 0.f, 0.f};

        #pragma unroll
        for (int ks = 0; ks < 8; ks++) {
            bf16x8 af0 = *reinterpret_cast<const bf16x8*>(&A_lds[rh * 32 + li][ks * 32 + grp * 8]);
            bf16x8 af1 = *reinterpret_cast<const bf16x8*>(&A_lds[rh * 32 + 16 + li][ks * 32 + grp * 8]);
            #pragma unroll
            for (int ni = 0; ni < 4; ni++) {
                acc[0][ni] = __builtin_amdgcn_mfma_f32_16x16x32_bf16(af0, Bf[ni][ks], acc[0][ni], 0, 0, 0);
                acc[1][ni] = __builtin_amdgcn_mfma_f32_16x16x32_bf16(af1, Bf[ni][ks], acc[1][ni], 0, 0, 0);
            }
        }

        float p[2][4];
        #pragma unroll
        for (int mi = 0; mi < 2; mi++)
            #pragma unroll
            for (int r4 = 0; r4 < 4; r4++) p[mi][r4] = 0.f;
        #pragma unroll
        for (int ni = 0; ni < 4; ni++)
            #pragma unroll
            for (int mi = 0; mi < 2; mi++)
                #pragma unroll
                for (int r4 = 0; r4 < 4; r4++) {
                    float y = acc[mi][ni][r4] + bias[ni];
                    y = y > 0.f ? y : 0.f;
                    p[mi][r4] += y * aw[ni];
                }
        #pragma unroll
        for (int mi = 0; mi < 2; mi++)
            #pragma unroll
            for (int r4 = 0; r4 < 4; r4++) {
                float v = p[mi][r4];
                #pragma unroll
                for (int m = 1; m < 16; m <<= 1) v += __shfl_xor(v, m);
                if (li == 0)
                    part[br][ch][rh * 32 + mi * 16 + grp * 4 + r4] = v;
            }
        __syncthreads();

        if (t < 128) {
            int b_ = t >> 6, lr = t & 63;
            int gr = row0 + lr;
            if (gr < N) {
                float val = part[b_][0][lr] + part[b_][1][lr];
                if (b_) g_self[gr] = val; else g_nb[gr] = val;
            }
        }
    }
}

// K2A: gate+mask -> pk = (row<<16)|bf16(mv). 4 edges/thread (R17 form).
__global__ __launch_bounds__(256) void k2a_gate(
    const int* __restrict__ row, const int* __restrict__ col,
    const float* __restrict__ values, const float* __restrict__ noise,
    const float* __restrict__ g_nb, const float* __restrict__ g_self,
    const float* __restrict__ b_att, unsigned* __restrict__ pk, int E)
{
    int i = (blockIdx.x * 256 + threadIdx.x) * 4;
    if (i >= E) return;
    const float ba = b_att[0];
    if (i + 3 < E) {
        int4   r4 = *reinterpret_cast<const int4*>(row + i);
        int4   c4 = *reinterpret_cast<const int4*>(col + i);
        float4 v4 = *reinterpret_cast<const float4*>(values + i);
        float4 u4 = *reinterpret_cast<const float4*>(noise + i);
        int   rr[4] = { r4.x, r4.y, r4.z, r4.w };
        int   cc[4] = { c4.x, c4.y, c4.z, c4.w };
        float vv[4] = { v4.x, v4.y, v4.z, v4.w };
        float uu[4] = { u4.x, u4.y, u4.z, u4.w };
        float gn[4], gs[4];
        #pragma unroll
        for (int j = 0; j < 4; j++) { gn[j] = g_nb[rr[j]]; gs[j] = g_self[cc[j]]; }
        unsigned pkv[4];
        #pragma unroll
        for (int j = 0; j < 4; j++) {
            float u    = uu[j] + 1e-7f;
            float la   = gn[j] + gs[j] + ba;
            float gate = u / (u + (1.f - u) * __expf(-la));
            float mask = fminf(fmaxf(gate * 1.6f - 0.5f, 0.f), 1.f);
            pkv[j] = ((unsigned)rr[j] << 16) | (unsigned)f2bf(vv[j] * mask);
        }
        *reinterpret_cast<uint4*>(pk + i) = make_uint4(pkv[0], pkv[1], pkv[2], pkv[3]);
    } else {
        for (int j = 0; j < 4 && i + j < E; j++) {
            int e = i + j;
            int   r = row[e];
            float u    = noise[e] + 1e-7f;
            float la   = g_nb[r] + g_self[col[e]] + ba;
            float gate = u / (u + (1.f - u) * __expf(-la));
            float mask = fminf(fmaxf(gate * 1.6f - 0.5f, 0.f), 1.f);
            pk[e] = ((unsigned)r << 16) | (unsigned)f2bf(values[e] * mask);
        }
    }
}

// K2Q: quartered LDS rowsum scatter over the packed stream. NSL*4 = 256 blocks
// x 1024 thr, 50KB LDS (1/CU, 16 waves). bf16 partial flush.
__global__ __launch_bounds__(1024) void k2q_scatter(
    const unsigned* __restrict__ pk, ushort* __restrict__ priv, int E, int ES)
{
    __shared__ float acc[QSH];
    const int s  = blockIdx.x >> 2;
    const int q  = blockIdx.x & 3;
    const int t  = threadIdx.x;
    const int lo = q * QSH;

    for (int i = t; i < QSH; i += 1024) acc[i] = 0.f;
    __syncthreads();

    const int base = s * ES;
    int end = base + ES; if (end > E) end = E;

    int i = base + t * 4;
    for (; i + 3 < end; i += 4096) {
        uint4 p4 = *reinterpret_cast<const uint4*>(pk + i);
        unsigned p; int d; float m;
        p = p4.x; d = (int)(p >> 16) - lo; m = bf2f(p & 0xffffu);
        if ((unsigned)d < (unsigned)QSH && m != 0.f) atomicAdd(&acc[d], m);
        p = p4.y; d = (int)(p >> 16) - lo; m = bf2f(p & 0xffffu);
        if ((unsigned)d < (unsigned)QSH && m != 0.f) atomicAdd(&acc[d], m);
        p = p4.z; d = (int)(p >> 16) - lo; m = bf2f(p & 0xffffu);
        if ((unsigned)d < (unsigned)QSH && m != 0.f) atomicAdd(&acc[d], m);
        p = p4.w; d = (int)(p >> 16) - lo; m = bf2f(p & 0xffffu);
        if ((unsigned)d < (unsigned)QSH && m != 0.f) atomicAdd(&acc[d], m);
    }
    for (; i < end; i++) {
        unsigned p = pk[i];
        int d = (int)(p >> 16) - lo;
        float m = bf2f(p & 0xffffu);
        if ((unsigned)d < (unsigned)QSH && m != 0.f) atomicAdd(&acc[d], m);
    }
    __syncthreads();

    ushort* dst = priv + (size_t)s * (4 * QSH) + lo;
    for (int j = t * 2; j < QSH; j += 2048) {
        unsigned pkk = (unsigned)f2bf(acc[j]) | ((unsigned)f2bf(acc[j + 1]) << 16);
        *reinterpret_cast<unsigned*>(dst + j) = pkk;
    }
}

// K2C: disb[n] = bf16(rsqrt(1e-10 + sum over NSL bf16 slice partials)).
__global__ __launch_bounds__(256) void k2c_reduce(
    const ushort* __restrict__ priv, ushort* __restrict__ disb, int N)
{
    int n0 = (blockIdx.x * 256 + threadIdx.x) * 2;
    if (n0 >= N) return;
    float s0 = 1e-10f, s1 = 1e-10f;
    for (int p = 0; p < NSL; p++) {
        unsigned v = *reinterpret_cast<const unsigned*>(priv + (size_t)p * (4 * QSH) + n0);
        s0 += bf2f(v & 0xffffu);
        s1 += bf2f(v >> 16);
    }
    unsigned o = (unsigned)f2bf(rsqrtf(s0)) | ((unsigned)f2bf(rsqrtf(s1)) << 16);
    *reinterpret_cast<unsigned*>(disb + n0) = o;
}

// K3 (lds): stage full bf16 dis table into LDS; read pk + col; write out once.
__global__ __launch_bounds__(1024) void k3_edge2_lds(
    const unsigned* __restrict__ pk, const int* __restrict__ col,
    float* __restrict__ out, const ushort* __restrict__ disb,
    int Npad2, int E, int EB)
{
    __shared__ ushort ldis[NMAXL];
    const int t = threadIdx.x;
    {
        const unsigned* src = reinterpret_cast<const unsigned*>(disb);
        unsigned* dst = reinterpret_cast<unsigned*>(ldis);
        const int nw = Npad2 >> 1;
        for (int i = t; i < nw; i += 1024) dst[i] = src[i];
    }
    __syncthreads();

    const int base = blockIdx.x * EB;
    int end = base + EB; if (end > E) end = E;

    int i = base + t * 4;
    for (; i + 3 < end; i += 4096) {
        uint4 p4 = *reinterpret_cast<const uint4*>(pk + i);
        int4  c4 = *reinterpret_cast<const int4*>(col + i);
        float4 o;
        o.x = bf2f(p4.x & 0xffffu) * bf2f(ldis[p4.x >> 16]) * bf2f(ldis[c4.x]);
        o.y = bf2f(p4.y & 0xffffu) * bf2f(ldis[p4.y >> 16]) * bf2f(ldis[c4.y]);
        o.z = bf2f(p4.z & 0xffffu) * bf2f(ldis[p4.z >> 16]) * bf2f(ldis[c4.z]);
        o.w = bf2f(p4.w & 0xffffu) * bf2f(ldis[p4.w >> 16]) * bf2f(ldis[c4.w]);
        *reinterpret_cast<float4*>(out + i) = o;
    }
    for (; i < end; i++) {
        unsigned p = pk[i];
        out[i] = bf2f(p & 0xffffu) * bf2f(ldis[p >> 16]) * bf2f(ldis[col[i]]);
    }
}

// ---- fallback path (N too large for LDS structures) ----
__global__ __launch_bounds__(256) void k2_atomic_fb(
    const int* __restrict__ row, const int* __restrict__ col,
    const float* __restrict__ values, const float* __restrict__ noise,
    const float* __restrict__ g_nb, const float* __restrict__ g_self,
    const float* __restrict__ b_att,
    float* __restrict__ out, float* __restrict__ dis, int E)
{
    int e = blockIdx.x * 256 + threadIdx.x;
    if (e >= E) return;
    int   r = row[e], c = col[e];
    float u = noise[e] + 1e-7f;
    float la = g_nb[r] + g_self[c] + b_att[0];
    float gate = u / (u + (1.f - u) * __expf(-la));
    float mask = fminf(fmaxf(gate * 1.6f - 0.5f, 0.f), 1.f);
    float m = values[e] * mask;
    out[e] = m;
    if (m != 0.f) atomicAdd(&dis[r], m);
}
__global__ __launch_bounds__(256) void k2c_rsqrt_fb(float* __restrict__ dis, int N)
{
    int n = blockIdx.x * 256 + threadIdx.x;
    if (n < N) dis[n] = rsqrtf(dis[n]);
}
__global__ __launch_bounds__(256) void k3_edge2_fb(
    const int* __restrict__ row, const int* __restrict__ col,
    float* __restrict__ out, const float* __restrict__ dis, int E)
{
    int e = blockIdx.x * 256 + threadIdx.x;
    if (e >= E) return;
    out[e] = out[e] * dis[row[e]] * dis[col[e]];
}

extern "C" void kernel_launch(void* const* d_in, const int* in_sizes, int n_in,
                              void* d_out, int out_size, void* d_ws, size_t ws_size,
                              hipStream_t stream) {
    const float* x      = (const float*)d_in[0];
    const float* W_nb   = (const float*)d_in[1];
    const float* b_nb   = (const float*)d_in[2];
    const float* W_self = (const float*)d_in[3];
    const float* b_self = (const float*)d_in[4];
    const float* W_att  = (const float*)d_in[5];
    const float* b_att  = (const float*)d_in[6];
    const float* values = (const float*)d_in[7];
    const float* noise  = (const float*)d_in[8];
    const int*   row    = (const int*)d_in[9];
    const int*   col    = (const int*)d_in[10];

    const int N = in_sizes[0] / D_DIM;
    const int E = in_sizes[7];
    float* out = (float*)d_out;

    char* ws = (char*)d_ws;
    ushort* Wt     = (ushort*)ws;                       // 131072 B, row-major [hcat][k]
    float*  g_nb   = (float*)(ws + 131072);             // N
    float*  g_self = g_nb + N;                          // N
    float*  dis    = g_self + N;                        // N f32 (fallback) / bf16 alias
    ushort* disb   = (ushort*)dis;                      // Npad2 bf16 (lds path)
    ushort* priv   = (ushort*)(dis + N);                // NSL * NMAXL bf16 (~6.4MB)
    size_t pk_off  = 131072 + (size_t)3 * N * 4 + (size_t)NSL * NMAXL * 2;
    pk_off = (pk_off + 15) & ~(size_t)15;
    unsigned* pk   = (unsigned*)(ws + pk_off);          // E uints (~3.2MB)
    size_t xbf_off = pk_off + (size_t)E * 4;
    xbf_off = (xbf_off + 15) & ~(size_t)15;
    ushort* xbf    = (ushort*)(ws + xbf_off);           // nt16*4096 bf16 (~25.6MB)

    const int Npad2 = (N + 1) & ~1;
    const int nt16  = (N + 15) / 16;
    const int nt32  = (nt16 + 1) / 2;
    int ES = ((E + NSL - 1) / NSL + 3) & ~3;
    size_t need = pk_off + (size_t)E * 4;
    bool lds_path = (N <= NMAXL) && (need <= ws_size);
    bool xbf_path = (xbf_off + (size_t)nt16 * 4096 * 2 <= ws_size);

    int work0 = 2 * H_DIM * D_DIM;
    if (N > work0) work0 = N;
    if (xbf_path && N * 32 > work0) work0 = N * 32;
    k0_init<<<(work0 + 255) / 256, 256, 0, stream>>>(x, W_nb, W_self, Wt, xbf, dis,
                                                     N, lds_path ? 0 : 1, xbf_path ? 1 : 0);

    if (xbf_path) {
        int gpairs = nt32 < 256 ? nt32 : 256;
        k1_ldsb<<<gpairs * 2, 256, 0, stream>>>(xbf, Wt, b_nb, b_self, W_att,
                                                g_nb, g_self, N, nt16, nt32);
    } else {
        const int nt64 = (N + 63) / 64;
        k1_gemm_f<<<256, 512, 0, stream>>>(x, Wt, b_nb, b_self, W_att, g_nb, g_self, N, nt64);
    }

    if (lds_path) {
        int eb4 = ((E + 3) / 4 + 255) / 256;
        k2a_gate<<<eb4, 256, 0, stream>>>(row, col, values, noise, g_nb, g_self,
                                          b_att, pk, E);
        k2q_scatter<<<NSL * 4, 1024, 0, stream>>>(pk, priv, E, ES);
        k2c_reduce<<<((N + 1) / 2 + 255) / 256, 256, 0, stream>>>(priv, disb, N);
        int EB = ((E + 255) / 256 + 3) & ~3;
        k3_edge2_lds<<<256, 1024, 0, stream>>>(pk, col, out, disb, Npad2, E, EB);
    } else {
        k2_atomic_fb<<<(E + 255) / 256, 256, 0, stream>>>(row, col, values, noise,
                                                          g_nb, g_self, b_att, out, dis, E);
        k2c_rsqrt_fb<<<(N + 255) / 256, 256, 0, stream>>>(dis, N);
        k3_edge2_fb<<<(E + 255) / 256, 256, 0, stream>>>(row, col, out, dis, E);
    }
}

// Round 22
// 62.658 us; speedup vs baseline: 1.0741x; 1.0741x over previous
//
#include <hip/hip_runtime.h>
#include <hip/hip_bf16.h>

typedef __attribute__((ext_vector_type(8))) short bf16x8;
typedef __attribute__((ext_vector_type(4))) float f32x4;

#define D_DIM 256   // input feature dim
#define H_DIM 128   // hidden dim per branch
#define QSH 12544   // rows per quarter; LDS f32 acc = 50176 B
#define NSL 64      // edge slices (k2q grid = NSL*4 = 256 blocks, 1/CU)
#define NMAXL (4 * QSH)   // max N for lds path (=> 100352 B bf16 dis LDS)

// RNE float->bf16 (bit pattern)
__device__ inline ushort f2bf(float f) {
    union { float f; unsigned u; } a; a.f = f;
    unsigned r = a.u + 0x7fffu + ((a.u >> 16) & 1u);
    return (ushort)(r >> 16);
}
__device__ inline float bf2f(unsigned hi16) {
    union { unsigned u; float f; } a; a.u = hi16 << 16;
    return a.f;
}

// K0: build Wt in FRAGMENT-MAJOR layout (R13). Optionally init dis for fallback.
// fragid = i>>12 (0..15): Wt[fragid*4096 + ks*512 + lane*8 + e] = W[k][h],
// h = (fragid>>2 &1)*64 ... encoded via cg/ni decomposition below.
__global__ void k0_init(const float* __restrict__ W_nb, const float* __restrict__ W_self,
                        ushort* __restrict__ Wt, float* __restrict__ dis, int N, int init_dis) {
    int i = blockIdx.x * 256 + threadIdx.x;
    if (i < 2 * H_DIM * D_DIM) {
        int j    = i & 7;
        int lane = (i >> 3) & 63;
        int ks   = (i >> 9) & 7;
        int ni   = (i >> 12) & 3;
        int cg   = i >> 14;          // 0..3
        int li   = lane & 15;
        int grp  = lane >> 4;
        int h    = (cg & 1) * 64 + ni * 16 + li;
        int k    = ks * 32 + grp * 8 + j;
        const float* W = (cg >> 1) ? W_self : W_nb;
        Wt[i] = f2bf(W[k * H_DIM + h]);
    }
    if (init_dis && i < N) dis[i] = 1e-10f;
}

// K1 (8-wave, register-resident B): 512 thr = 8 waves; wave w owns 32 h-cols
// (hcat [w*32, w*32+32)), so Bf[2][8] = 64 VGPR — FITS in registers (R18's
// VGPR_Count=112 proved the old 128-VGPR Bf[4][8] was spilled and re-read
// from L2 every tile ≈ 800MB ≈ 23us). acc[4][2]=32 VGPR. Grid min(ntiles,512)
// -> 2 x 35KB blocks/CU co-resident for stage/MFMA overlap.
__global__ __launch_bounds__(512, 2) void k1_gemm8(
    const float* __restrict__ x, const ushort* __restrict__ Wt,
    const float* __restrict__ b_nb, const float* __restrict__ b_self,
    const float* __restrict__ W_att,
    float* __restrict__ g_nb, float* __restrict__ g_self, int N, int ntiles)
{
    __shared__ __align__(16) ushort A_lds[64][264];
    __shared__ float part[8][64];

    const int t    = threadIdx.x;
    const int lane = t & 63;
    const int w    = t >> 6;        // 0..7: col-group wave
    const int br   = w >> 2;        // 0: nb, 1: self
    const int li   = lane & 15;
    const int grp  = lane >> 4;

    float bias[2], aw[2];
    #pragma unroll
    for (int ni2 = 0; ni2 < 2; ni2++) {
        int hh = (w & 3) * 32 + ni2 * 16 + li;     // within-branch col 0..127
        bias[ni2] = br ? b_self[hh] : b_nb[hh];
        aw[ni2]   = W_att[br * H_DIM + hh];
    }

    // register-resident B fragments: fragid = w*2 + ni2 (frag-major Wt)
    bf16x8 Bf[2][8];
    #pragma unroll
    for (int ni2 = 0; ni2 < 2; ni2++)
        #pragma unroll
        for (int ks = 0; ks < 8; ks++)
            Bf[ni2][ks] = *reinterpret_cast<const bf16x8*>(
                Wt + (((size_t)(w * 2 + ni2) * 8 + ks) << 9) + lane * 8);

    const int sr = t >> 3;          // 0..63 staging row
    const int sc = t & 7;           // 0..7  staging col chunk

    for (int rt = blockIdx.x; rt < ntiles; rt += gridDim.x) {
        const int row0 = rt * 64;

        __syncthreads();            // A_lds + part free
        // ---- stage A: 64 rows x 256 f32 -> bf16 LDS ----
        {
            const int gr = row0 + sr;
            const bool v = gr < N;
            const float4* src = reinterpret_cast<const float4*>(x + (size_t)gr * D_DIM);
            #pragma unroll
            for (int j = 0; j < 8; j++) {
                int c4 = sc + j * 8;
                ushort4 o;
                if (v) {
                    float4 f = src[c4];
                    o.x = f2bf(f.x); o.y = f2bf(f.y); o.z = f2bf(f.z); o.w = f2bf(f.w);
                } else { o.x = 0; o.y = 0; o.z = 0; o.w = 0; }
                *reinterpret_cast<ushort4*>(&A_lds[sr][c4 * 4]) = o;
            }
        }
        __syncthreads();

        // ---- MFMA over K=256: 4 row-groups x 2 cols x 8 kslices ----
        f32x4 acc[4][2];
        #pragma unroll
        for (int mi = 0; mi < 4; mi++)
            #pragma unroll
            for (int ni2 = 0; ni2 < 2; ni2++) acc[mi][ni2] = f32x4{0.f, 0.f, 0.f, 0.f};

        #pragma unroll
        for (int ks = 0; ks < 8; ks++) {
            #pragma unroll
            for (int mi = 0; mi < 4; mi++) {
                bf16x8 af = *reinterpret_cast<const bf16x8*>(
                    &A_lds[mi * 16 + li][ks * 32 + grp * 8]);
                acc[mi][0] = __builtin_amdgcn_mfma_f32_16x16x32_bf16(af, Bf[0][ks], acc[mi][0], 0, 0, 0);
                acc[mi][1] = __builtin_amdgcn_mfma_f32_16x16x32_bf16(af, Bf[1][ks], acc[mi][1], 0, 0, 0);
            }
        }

        // ---- epilogue: bias+relu+aw, shfl-reduce over the 16 li lanes ----
        #pragma unroll
        for (int mi = 0; mi < 4; mi++)
            #pragma unroll
            for (int r4 = 0; r4 < 4; r4++) {
                float y0 = acc[mi][0][r4] + bias[0];
                float y1 = acc[mi][1][r4] + bias[1];
                y0 = y0 > 0.f ? y0 : 0.f;
                y1 = y1 > 0.f ? y1 : 0.f;
                float s = y0 * aw[0] + y1 * aw[1];
                #pragma unroll
                for (int m = 1; m < 16; m <<= 1) s += __shfl_xor(s, m);
                if (li == 0) part[w][mi * 16 + grp * 4 + r4] = s;
            }
        __syncthreads();

        if (t < 128) {
            int b_ = t >> 6, lr = t & 63;
            int gr = row0 + lr;
            if (gr < N) {
                float val = part[b_ * 4 + 0][lr] + part[b_ * 4 + 1][lr]
                          + part[b_ * 4 + 2][lr] + part[b_ * 4 + 3][lr];
                if (b_) g_self[gr] = val; else g_nb[gr] = val;
            }
        }
    }
}

// K2A: gate+mask -> pk = (row<<16)|bf16(mv). 4 edges/thread (R17 form).
__global__ __launch_bounds__(256) void k2a_gate(
    const int* __restrict__ row, const int* __restrict__ col,
    const float* __restrict__ values, const float* __restrict__ noise,
    const float* __restrict__ g_nb, const float* __restrict__ g_self,
    const float* __restrict__ b_att, unsigned* __restrict__ pk, int E)
{
    int i = (blockIdx.x * 256 + threadIdx.x) * 4;
    if (i >= E) return;
    const float ba = b_att[0];
    if (i + 3 < E) {
        int4   r4 = *reinterpret_cast<const int4*>(row + i);
        int4   c4 = *reinterpret_cast<const int4*>(col + i);
        float4 v4 = *reinterpret_cast<const float4*>(values + i);
        float4 u4 = *reinterpret_cast<const float4*>(noise + i);
        int   rr[4] = { r4.x, r4.y, r4.z, r4.w };
        int   cc[4] = { c4.x, c4.y, c4.z, c4.w };
        float vv[4] = { v4.x, v4.y, v4.z, v4.w };
        float uu[4] = { u4.x, u4.y, u4.z, u4.w };
        float gn[4], gs[4];
        #pragma unroll
        for (int j = 0; j < 4; j++) { gn[j] = g_nb[rr[j]]; gs[j] = g_self[cc[j]]; }
        unsigned pkv[4];
        #pragma unroll
        for (int j = 0; j < 4; j++) {
            float u    = uu[j] + 1e-7f;
            float la   = gn[j] + gs[j] + ba;
            float gate = u / (u + (1.f - u) * __expf(-la));
            float mask = fminf(fmaxf(gate * 1.6f - 0.5f, 0.f), 1.f);
            pkv[j] = ((unsigned)rr[j] << 16) | (unsigned)f2bf(vv[j] * mask);
        }
        *reinterpret_cast<uint4*>(pk + i) = make_uint4(pkv[0], pkv[1], pkv[2], pkv[3]);
    } else {
        for (int j = 0; j < 4 && i + j < E; j++) {
            int e = i + j;
            int   r = row[e];
            float u    = noise[e] + 1e-7f;
            float la   = g_nb[r] + g_self[col[e]] + ba;
            float gate = u / (u + (1.f - u) * __expf(-la));
            float mask = fminf(fmaxf(gate * 1.6f - 0.5f, 0.f), 1.f);
            pk[e] = ((unsigned)r << 16) | (unsigned)f2bf(values[e] * mask);
        }
    }
}

// K2Q: quartered LDS rowsum scatter over the packed stream. NSL*4 = 256 blocks
// x 1024 thr, 50KB LDS (1/CU, 16 waves). bf16 partial flush.
__global__ __launch_bounds__(1024) void k2q_scatter(
    const unsigned* __restrict__ pk, ushort* __restrict__ priv, int E, int ES)
{
    __shared__ float acc[QSH];
    const int s  = blockIdx.x >> 2;
    const int q  = blockIdx.x & 3;
    const int t  = threadIdx.x;
    const int lo = q * QSH;

    for (int i = t; i < QSH; i += 1024) acc[i] = 0.f;
    __syncthreads();

    const int base = s * ES;            // ES multiple of 4 -> 16B aligned
    int end = base + ES; if (end > E) end = E;

    int i = base + t * 4;
    for (; i + 3 < end; i += 4096) {
        uint4 p4 = *reinterpret_cast<const uint4*>(pk + i);
        unsigned p; int d; float m;
        p = p4.x; d = (int)(p >> 16) - lo; m = bf2f(p & 0xffffu);
        if ((unsigned)d < (unsigned)QSH && m != 0.f) atomicAdd(&acc[d], m);
        p = p4.y; d = (int)(p >> 16) - lo; m = bf2f(p & 0xffffu);
        if ((unsigned)d < (unsigned)QSH && m != 0.f) atomicAdd(&acc[d], m);
        p = p4.z; d = (int)(p >> 16) - lo; m = bf2f(p & 0xffffu);
        if ((unsigned)d < (unsigned)QSH && m != 0.f) atomicAdd(&acc[d], m);
        p = p4.w; d = (int)(p >> 16) - lo; m = bf2f(p & 0xffffu);
        if ((unsigned)d < (unsigned)QSH && m != 0.f) atomicAdd(&acc[d], m);
    }
    for (; i < end; i++) {              // scalar tail
        unsigned p = pk[i];
        int d = (int)(p >> 16) - lo;
        float m = bf2f(p & 0xffffu);
        if ((unsigned)d < (unsigned)QSH && m != 0.f) atomicAdd(&acc[d], m);
    }
    __syncthreads();

    // flush bf16 partials: 2 rows packed per uint, coalesced
    ushort* dst = priv + (size_t)s * (4 * QSH) + lo;
    for (int j = t * 2; j < QSH; j += 2048) {
        unsigned pkk = (unsigned)f2bf(acc[j]) | ((unsigned)f2bf(acc[j + 1]) << 16);
        *reinterpret_cast<unsigned*>(dst + j) = pkk;
    }
}

// K2C: disb[n] = bf16(rsqrt(1e-10 + sum over NSL bf16 slice partials)).
__global__ __launch_bounds__(256) void k2c_reduce(
    const ushort* __restrict__ priv, ushort* __restrict__ disb, int N)
{
    int n0 = (blockIdx.x * 256 + threadIdx.x) * 2;
    if (n0 >= N) return;
    float s0 = 1e-10f, s1 = 1e-10f;
    for (int p = 0; p < NSL; p++) {
        unsigned v = *reinterpret_cast<const unsigned*>(priv + (size_t)p * (4 * QSH) + n0);
        s0 += bf2f(v & 0xffffu);
        s1 += bf2f(v >> 16);
    }
    unsigned o = (unsigned)f2bf(rsqrtf(s0)) | ((unsigned)f2bf(rsqrtf(s1)) << 16);
    *reinterpret_cast<unsigned*>(disb + n0) = o;
}

// K3 (lds): stage full bf16 dis table into LDS; read pk (row+mv) + col; write
// out once, coalesced. 256 blocks x 1024 thr, 100KB LDS.
__global__ __launch_bounds__(1024) void k3_edge2_lds(
    const unsigned* __restrict__ pk, const int* __restrict__ col,
    float* __restrict__ out, const ushort* __restrict__ disb,
    int Npad2, int E, int EB)
{
    __shared__ ushort ldis[NMAXL];
    const int t = threadIdx.x;
    {
        const unsigned* src = reinterpret_cast<const unsigned*>(disb);
        unsigned* dst = reinterpret_cast<unsigned*>(ldis);
        const int nw = Npad2 >> 1;
        for (int i = t; i < nw; i += 1024) dst[i] = src[i];
    }
    __syncthreads();

    const int base = blockIdx.x * EB;
    int end = base + EB; if (end > E) end = E;

    int i = base + t * 4;
    for (; i + 3 < end; i += 4096) {
        uint4 p4 = *reinterpret_cast<const uint4*>(pk + i);
        int4  c4 = *reinterpret_cast<const int4*>(col + i);
        float4 o;
        o.x = bf2f(p4.x & 0xffffu) * bf2f(ldis[p4.x >> 16]) * bf2f(ldis[c4.x]);
        o.y = bf2f(p4.y & 0xffffu) * bf2f(ldis[p4.y >> 16]) * bf2f(ldis[c4.y]);
        o.z = bf2f(p4.z & 0xffffu) * bf2f(ldis[p4.z >> 16]) * bf2f(ldis[c4.z]);
        o.w = bf2f(p4.w & 0xffffu) * bf2f(ldis[p4.w >> 16]) * bf2f(ldis[c4.w]);
        *reinterpret_cast<float4*>(out + i) = o;
    }
    for (; i < end; i++) {
        unsigned p = pk[i];
        out[i] = bf2f(p & 0xffffu) * bf2f(ldis[p >> 16]) * bf2f(ldis[col[i]]);
    }
}

// ---- fallback path (N too large for LDS structures) ----
__global__ __launch_bounds__(256) void k2_atomic_fb(
    const int* __restrict__ row, const int* __restrict__ col,
    const float* __restrict__ values, const float* __restrict__ noise,
    const float* __restrict__ g_nb, const float* __restrict__ g_self,
    const float* __restrict__ b_att,
    float* __restrict__ out, float* __restrict__ dis, int E)
{
    int e = blockIdx.x * 256 + threadIdx.x;
    if (e >= E) return;
    int   r = row[e], c = col[e];
    float u = noise[e] + 1e-7f;
    float la = g_nb[r] + g_self[c] + b_att[0];
    float gate = u / (u + (1.f - u) * __expf(-la));
    float mask = fminf(fmaxf(gate * 1.6f - 0.5f, 0.f), 1.f);
    float m = values[e] * mask;
    out[e] = m;
    if (m != 0.f) atomicAdd(&dis[r], m);
}
__global__ __launch_bounds__(256) void k2c_rsqrt_fb(float* __restrict__ dis, int N)
{
    int n = blockIdx.x * 256 + threadIdx.x;
    if (n < N) dis[n] = rsqrtf(dis[n]);
}
__global__ __launch_bounds__(256) void k3_edge2_fb(
    const int* __restrict__ row, const int* __restrict__ col,
    float* __restrict__ out, const float* __restrict__ dis, int E)
{
    int e = blockIdx.x * 256 + threadIdx.x;
    if (e >= E) return;
    out[e] = out[e] * dis[row[e]] * dis[col[e]];
}

extern "C" void kernel_launch(void* const* d_in, const int* in_sizes, int n_in,
                              void* d_out, int out_size, void* d_ws, size_t ws_size,
                              hipStream_t stream) {
    const float* x      = (const float*)d_in[0];
    const float* W_nb   = (const float*)d_in[1];
    const float* b_nb   = (const float*)d_in[2];
    const float* W_self = (const float*)d_in[3];
    const float* b_self = (const float*)d_in[4];
    const float* W_att  = (const float*)d_in[5];
    const float* b_att  = (const float*)d_in[6];
    const float* values = (const float*)d_in[7];
    const float* noise  = (const float*)d_in[8];
    const int*   row    = (const int*)d_in[9];
    const int*   col    = (const int*)d_in[10];

    const int N = in_sizes[0] / D_DIM;
    const int E = in_sizes[7];
    float* out = (float*)d_out;

    char* ws = (char*)d_ws;
    ushort* Wt     = (ushort*)ws;                       // 131072 B (frag-major)
    float*  g_nb   = (float*)(ws + 131072);             // N
    float*  g_self = g_nb + N;                          // N
    float*  dis    = g_self + N;                        // N f32 (fallback) / bf16 alias
    ushort* disb   = (ushort*)dis;                      // Npad2 bf16 (lds path)
    ushort* priv   = (ushort*)(dis + N);                // NSL * NMAXL bf16 (~6.4MB)
    size_t pk_off  = 131072 + (size_t)3 * N * 4 + (size_t)NSL * NMAXL * 2;
    pk_off = (pk_off + 15) & ~(size_t)15;
    unsigned* pk   = (unsigned*)(ws + pk_off);          // E uints (~3.2MB)

    const int Npad2 = (N + 1) & ~1;
    int ES = ((E + NSL - 1) / NSL + 3) & ~3;            // edges/slice, mult of 4
    size_t need = pk_off + (size_t)E * 4;
    bool lds_path = (N <= NMAXL) && (need <= ws_size);

    int init_n = 2 * H_DIM * D_DIM;
    if (N > init_n) init_n = N;
    k0_init<<<(init_n + 255) / 256, 256, 0, stream>>>(W_nb, W_self, Wt, dis, N, lds_path ? 0 : 1);

    const int ntiles = (N + 63) / 64;
    int k1grid = ntiles < 512 ? ntiles : 512;
    k1_gemm8<<<k1grid, 512, 0, stream>>>(x, Wt, b_nb, b_self, W_att, g_nb, g_self, N, ntiles);

    if (lds_path) {
        int eb4 = ((E + 3) / 4 + 255) / 256;
        k2a_gate<<<eb4, 256, 0, stream>>>(row, col, values, noise, g_nb, g_self,
                                          b_att, pk, E);
        k2q_scatter<<<NSL * 4, 1024, 0, stream>>>(pk, priv, E, ES);
        k2c_reduce<<<((N + 1) / 2 + 255) / 256, 256, 0, stream>>>(priv, disb, N);
        int EB = ((E + 255) / 256 + 3) & ~3;            // edges/block, mult of 4
        k3_edge2_lds<<<256, 1024, 0, stream>>>(pk, col, out, disb, Npad2, E, EB);
    } else {
        k2_atomic_fb<<<(E + 255) / 256, 256, 0, stream>>>(row, col, values, noise,
                                                          g_nb, g_self, b_att, out, dis, E);
        k2c_rsqrt_fb<<<(N + 255) / 256, 256, 0, stream>>>(dis, N);
        k3_edge2_fb<<<(E + 255) / 256, 256, 0, stream>>>(row, col, out, dis, E);
    }
}

// Round 23
// 58.300 us; speedup vs baseline: 1.1544x; 1.0748x over previous
//
#include <hip/hip_runtime.h>
#include <hip/hip_bf16.h>

typedef __attribute__((ext_vector_type(8))) short bf16x8;
typedef __attribute__((ext_vector_type(4))) float f32x4;

#define D_DIM 256   // input feature dim
#define H_DIM 128   // hidden dim per branch
#define QSH 12544   // rows per quarter; LDS f32 acc = 50176 B
#define NSL 64      // edge slices (k2q grid = NSL*4 = 256 blocks, 1/CU)
#define NMAXL (4 * QSH)   // max N for lds path (=> 100352 B bf16 dis LDS)

// RNE float->bf16 (bit pattern)
__device__ inline ushort f2bf(float f) {
    union { float f; unsigned u; } a; a.f = f;
    unsigned r = a.u + 0x7fffu + ((a.u >> 16) & 1u);
    return (ushort)(r >> 16);
}
__device__ inline float bf2f(unsigned hi16) {
    union { unsigned u; float f; } a; a.u = hi16 << 16;
    return a.f;
}

// K0: build Wt in FRAGMENT-MAJOR layout (R13). Optionally init dis for fallback.
__global__ void k0_init(const float* __restrict__ W_nb, const float* __restrict__ W_self,
                        ushort* __restrict__ Wt, float* __restrict__ dis, int N, int init_dis) {
    int i = blockIdx.x * 256 + threadIdx.x;
    if (i < 2 * H_DIM * D_DIM) {
        int j    = i & 7;
        int lane = (i >> 3) & 63;
        int ks   = (i >> 9) & 7;
        int ni   = (i >> 12) & 3;
        int cg   = i >> 14;          // 0..3
        int li   = lane & 15;
        int grp  = lane >> 4;
        int h    = (cg & 1) * 64 + ni * 16 + li;
        int k    = ks * 32 + grp * 8 + j;
        const float* W = (cg >> 1) ? W_self : W_nb;
        Wt[i] = f2bf(W[k * H_DIM + h]);
    }
    if (init_dis && i < N) dis[i] = 1e-10f;
}

// K1: persistent-B fused GEMM (R17 structure). ONE CHANGE: __launch_bounds__(512)
// with NO min-blocks arg. The old (512,2) meant 2 BLOCKS/CU = 16 waves/CU =
// 4 waves/SIMD -> VGPR cap 128 (R18 measured VGPR_Count=112): Bf[4][8]'s 128
// registers NEVER fit and were spilled to scratch, re-read every tile. Uncapped,
// Bf is truly register-resident (~220 VGPR, 1 block/CU, 2 waves/SIMD).
__global__ __launch_bounds__(512) void k1_gemm(
    const float* __restrict__ x, const ushort* __restrict__ Wt,
    const float* __restrict__ b_nb, const float* __restrict__ b_self,
    const float* __restrict__ W_att,
    float* __restrict__ g_nb, float* __restrict__ g_self, int N, int ntiles)
{
    __shared__ __align__(16) ushort A_lds[64][264];
    __shared__ float part[2][2][64];

    const int t    = threadIdx.x;
    const int lane = t & 63;
    const int w    = t >> 6;
    const int rh   = w >> 2;
    const int cg   = w & 3;
    const int br   = cg >> 1;
    const int ch   = cg & 1;
    const int li   = lane & 15;
    const int grp  = lane >> 4;

    float bias[4], aw[4];
    #pragma unroll
    for (int ni = 0; ni < 4; ni++) {
        int hh = ch * 64 + ni * 16 + li;
        bias[ni] = br ? b_self[hh] : b_nb[hh];
        aw[ni]   = W_att[br * H_DIM + hh];
    }

    // persistent B fragments — coalesced frag-major loads, register-resident
    bf16x8 Bf[4][8];
    #pragma unroll
    for (int ni = 0; ni < 4; ni++)
        #pragma unroll
        for (int ks = 0; ks < 8; ks++)
            Bf[ni][ks] = *reinterpret_cast<const bf16x8*>(
                Wt + (((size_t)(cg * 4 + ni) * 8 + ks) << 9) + lane * 8);

    const int sr = t >> 3;
    const int sc = t & 7;

    for (int rt = blockIdx.x; rt < ntiles; rt += gridDim.x) {
        const int row0 = rt * 64;

        __syncthreads();
        {
            const int gr = row0 + sr;
            const bool v = gr < N;
            const float4* src = reinterpret_cast<const float4*>(x + (size_t)gr * D_DIM);
            #pragma unroll
            for (int j = 0; j < 8; j++) {
                int c4 = sc + j * 8;
                ushort4 o;
                if (v) {
                    float4 f = src[c4];
                    o.x = f2bf(f.x); o.y = f2bf(f.y); o.z = f2bf(f.z); o.w = f2bf(f.w);
                } else { o.x = 0; o.y = 0; o.z = 0; o.w = 0; }
                *reinterpret_cast<ushort4*>(&A_lds[sr][c4 * 4]) = o;
            }
        }
        __syncthreads();

        f32x4 acc[2][4];
        #pragma unroll
        for (int mi = 0; mi < 2; mi++)
            #pragma unroll
            for (int ni = 0; ni < 4; ni++) acc[mi][ni] = f32x4{0.f, 0.f, 0.f, 0.f};

        #pragma unroll
        for (int ks = 0; ks < 8; ks++) {
            bf16x8 af0 = *reinterpret_cast<const bf16x8*>(&A_lds[rh * 32 + li][ks * 32 + grp * 8]);
            bf16x8 af1 = *reinterpret_cast<const bf16x8*>(&A_lds[rh * 32 + 16 + li][ks * 32 + grp * 8]);
            #pragma unroll
            for (int ni = 0; ni < 4; ni++) {
                acc[0][ni] = __builtin_amdgcn_mfma_f32_16x16x32_bf16(af0, Bf[ni][ks], acc[0][ni], 0, 0, 0);
                acc[1][ni] = __builtin_amdgcn_mfma_f32_16x16x32_bf16(af1, Bf[ni][ks], acc[1][ni], 0, 0, 0);
            }
        }

        float p[2][4];
        #pragma unroll
        for (int mi = 0; mi < 2; mi++)
            #pragma unroll
            for (int r4 = 0; r4 < 4; r4++) p[mi][r4] = 0.f;
        #pragma unroll
        for (int ni = 0; ni < 4; ni++)
            #pragma unroll
            for (int mi = 0; mi < 2; mi++)
                #pragma unroll
                for (int r4 = 0; r4 < 4; r4++) {
                    float y = acc[mi][ni][r4] + bias[ni];
                    y = y > 0.f ? y : 0.f;
                    p[mi][r4] += y * aw[ni];
                }
        #pragma unroll
        for (int mi = 0; mi < 2; mi++)
            #pragma unroll
            for (int r4 = 0; r4 < 4; r4++) {
                float v = p[mi][r4];
                #pragma unroll
                for (int m = 1; m < 16; m <<= 1) v += __shfl_xor(v, m);
                if (li == 0)
                    part[br][ch][rh * 32 + mi * 16 + grp * 4 + r4] = v;
            }
        __syncthreads();

        if (t < 128) {
            int b_ = t >> 6, lr = t & 63;
            int gr = row0 + lr;
            if (gr < N) {
                float val = part[b_][0][lr] + part[b_][1][lr];
                if (b_) g_self[gr] = val; else g_nb[gr] = val;
            }
        }
    }
}

// K2A: gate+mask -> pk = (row<<16)|bf16(mv). 4 edges/thread (R17 form).
__global__ __launch_bounds__(256) void k2a_gate(
    const int* __restrict__ row, const int* __restrict__ col,
    const float* __restrict__ values, const float* __restrict__ noise,
    const float* __restrict__ g_nb, const float* __restrict__ g_self,
    const float* __restrict__ b_att, unsigned* __restrict__ pk, int E)
{
    int i = (blockIdx.x * 256 + threadIdx.x) * 4;
    if (i >= E) return;
    const float ba = b_att[0];
    if (i + 3 < E) {
        int4   r4 = *reinterpret_cast<const int4*>(row + i);
        int4   c4 = *reinterpret_cast<const int4*>(col + i);
        float4 v4 = *reinterpret_cast<const float4*>(values + i);
        float4 u4 = *reinterpret_cast<const float4*>(noise + i);
        int   rr[4] = { r4.x, r4.y, r4.z, r4.w };
        int   cc[4] = { c4.x, c4.y, c4.z, c4.w };
        float vv[4] = { v4.x, v4.y, v4.z, v4.w };
        float uu[4] = { u4.x, u4.y, u4.z, u4.w };
        float gn[4], gs[4];
        #pragma unroll
        for (int j = 0; j < 4; j++) { gn[j] = g_nb[rr[j]]; gs[j] = g_self[cc[j]]; }
        unsigned pkv[4];
        #pragma unroll
        for (int j = 0; j < 4; j++) {
            float u    = uu[j] + 1e-7f;
            float la   = gn[j] + gs[j] + ba;
            float gate = u / (u + (1.f - u) * __expf(-la));
            float mask = fminf(fmaxf(gate * 1.6f - 0.5f, 0.f), 1.f);
            pkv[j] = ((unsigned)rr[j] << 16) | (unsigned)f2bf(vv[j] * mask);
        }
        *reinterpret_cast<uint4*>(pk + i) = make_uint4(pkv[0], pkv[1], pkv[2], pkv[3]);
    } else {
        for (int j = 0; j < 4 && i + j < E; j++) {
            int e = i + j;
            int   r = row[e];
            float u    = noise[e] + 1e-7f;
            float la   = g_nb[r] + g_self[col[e]] + ba;
            float gate = u / (u + (1.f - u) * __expf(-la));
            float mask = fminf(fmaxf(gate * 1.6f - 0.5f, 0.f), 1.f);
            pk[e] = ((unsigned)r << 16) | (unsigned)f2bf(values[e] * mask);
        }
    }
}

// K2Q: quartered LDS rowsum scatter over the packed stream. NSL*4 = 256 blocks
// x 1024 thr, 50KB LDS (1/CU, 16 waves). bf16 partial flush.
__global__ __launch_bounds__(1024) void k2q_scatter(
    const unsigned* __restrict__ pk, ushort* __restrict__ priv, int E, int ES)
{
    __shared__ float acc[QSH];
    const int s  = blockIdx.x >> 2;
    const int q  = blockIdx.x & 3;
    const int t  = threadIdx.x;
    const int lo = q * QSH;

    for (int i = t; i < QSH; i += 1024) acc[i] = 0.f;
    __syncthreads();

    const int base = s * ES;            // ES multiple of 4 -> 16B aligned
    int end = base + ES; if (end > E) end = E;

    int i = base + t * 4;
    for (; i + 3 < end; i += 4096) {
        uint4 p4 = *reinterpret_cast<const uint4*>(pk + i);
        unsigned p; int d; float m;
        p = p4.x; d = (int)(p >> 16) - lo; m = bf2f(p & 0xffffu);
        if ((unsigned)d < (unsigned)QSH && m != 0.f) atomicAdd(&acc[d], m);
        p = p4.y; d = (int)(p >> 16) - lo; m = bf2f(p & 0xffffu);
        if ((unsigned)d < (unsigned)QSH && m != 0.f) atomicAdd(&acc[d], m);
        p = p4.z; d = (int)(p >> 16) - lo; m = bf2f(p & 0xffffu);
        if ((unsigned)d < (unsigned)QSH && m != 0.f) atomicAdd(&acc[d], m);
        p = p4.w; d = (int)(p >> 16) - lo; m = bf2f(p & 0xffffu);
        if ((unsigned)d < (unsigned)QSH && m != 0.f) atomicAdd(&acc[d], m);
    }
    for (; i < end; i++) {              // scalar tail
        unsigned p = pk[i];
        int d = (int)(p >> 16) - lo;
        float m = bf2f(p & 0xffffu);
        if ((unsigned)d < (unsigned)QSH && m != 0.f) atomicAdd(&acc[d], m);
    }
    __syncthreads();

    // flush bf16 partials: 2 rows packed per uint, coalesced
    ushort* dst = priv + (size_t)s * (4 * QSH) + lo;
    for (int j = t * 2; j < QSH; j += 2048) {
        unsigned pkk = (unsigned)f2bf(acc[j]) | ((unsigned)f2bf(acc[j + 1]) << 16);
        *reinterpret_cast<unsigned*>(dst + j) = pkk;
    }
}

// K2C: disb[n] = bf16(rsqrt(1e-10 + sum over NSL bf16 slice partials)).
__global__ __launch_bounds__(256) void k2c_reduce(
    const ushort* __restrict__ priv, ushort* __restrict__ disb, int N)
{
    int n0 = (blockIdx.x * 256 + threadIdx.x) * 2;
    if (n0 >= N) return;
    float s0 = 1e-10f, s1 = 1e-10f;
    for (int p = 0; p < NSL; p++) {
        unsigned v = *reinterpret_cast<const unsigned*>(priv + (size_t)p * (4 * QSH) + n0);
        s0 += bf2f(v & 0xffffu);
        s1 += bf2f(v >> 16);
    }
    unsigned o = (unsigned)f2bf(rsqrtf(s0)) | ((unsigned)f2bf(rsqrtf(s1)) << 16);
    *reinterpret_cast<unsigned*>(disb + n0) = o;
}

// K3 (lds): stage full bf16 dis table into LDS; read pk (row+mv) + col; write
// out once, coalesced. 256 blocks x 1024 thr, 100KB LDS.
__global__ __launch_bounds__(1024) void k3_edge2_lds(
    const unsigned* __restrict__ pk, const int* __restrict__ col,
    float* __restrict__ out, const ushort* __restrict__ disb,
    int Npad2, int E, int EB)
{
    __shared__ ushort ldis[NMAXL];
    const int t = threadIdx.x;
    {
        const unsigned* src = reinterpret_cast<const unsigned*>(disb);
        unsigned* dst = reinterpret_cast<unsigned*>(ldis);
        const int nw = Npad2 >> 1;
        for (int i = t; i < nw; i += 1024) dst[i] = src[i];
    }
    __syncthreads();

    const int base = blockIdx.x * EB;
    int end = base + EB; if (end > E) end = E;

    int i = base + t * 4;
    for (; i + 3 < end; i += 4096) {
        uint4 p4 = *reinterpret_cast<const uint4*>(pk + i);
        int4  c4 = *reinterpret_cast<const int4*>(col + i);
        float4 o;
        o.x = bf2f(p4.x & 0xffffu) * bf2f(ldis[p4.x >> 16]) * bf2f(ldis[c4.x]);
        o.y = bf2f(p4.y & 0xffffu) * bf2f(ldis[p4.y >> 16]) * bf2f(ldis[c4.y]);
        o.z = bf2f(p4.z & 0xffffu) * bf2f(ldis[p4.z >> 16]) * bf2f(ldis[c4.z]);
        o.w = bf2f(p4.w & 0xffffu) * bf2f(ldis[p4.w >> 16]) * bf2f(ldis[c4.w]);
        *reinterpret_cast<float4*>(out + i) = o;
    }
    for (; i < end; i++) {
        unsigned p = pk[i];
        out[i] = bf2f(p & 0xffffu) * bf2f(ldis[p >> 16]) * bf2f(ldis[col[i]]);
    }
}

// ---- fallback path (N too large for LDS structures) ----
__global__ __launch_bounds__(256) void k2_atomic_fb(
    const int* __restrict__ row, const int* __restrict__ col,
    const float* __restrict__ values, const float* __restrict__ noise,
    const float* __restrict__ g_nb, const float* __restrict__ g_self,
    const float* __restrict__ b_att,
    float* __restrict__ out, float* __restrict__ dis, int E)
{
    int e = blockIdx.x * 256 + threadIdx.x;
    if (e >= E) return;
    int   r = row[e], c = col[e];
    float u = noise[e] + 1e-7f;
    float la = g_nb[r] + g_self[c] + b_att[0];
    float gate = u / (u + (1.f - u) * __expf(-la));
    float mask = fminf(fmaxf(gate * 1.6f - 0.5f, 0.f), 1.f);
    float m = values[e] * mask;
    out[e] = m;
    if (m != 0.f) atomicAdd(&dis[r], m);
}
__global__ __launch_bounds__(256) void k2c_rsqrt_fb(float* __restrict__ dis, int N)
{
    int n = blockIdx.x * 256 + threadIdx.x;
    if (n < N) dis[n] = rsqrtf(dis[n]);
}
__global__ __launch_bounds__(256) void k3_edge2_fb(
    const int* __restrict__ row, const int* __restrict__ col,
    float* __restrict__ out, const float* __restrict__ dis, int E)
{
    int e = blockIdx.x * 256 + threadIdx.x;
    if (e >= E) return;
    out[e] = out[e] * dis[row[e]] * dis[col[e]];
}

extern "C" void kernel_launch(void* const* d_in, const int* in_sizes, int n_in,
                              void* d_out, int out_size, void* d_ws, size_t ws_size,
                              hipStream_t stream) {
    const float* x      = (const float*)d_in[0];
    const float* W_nb   = (const float*)d_in[1];
    const float* b_nb   = (const float*)d_in[2];
    const float* W_self = (const float*)d_in[3];
    const float* b_self = (const float*)d_in[4];
    const float* W_att  = (const float*)d_in[5];
    const float* b_att  = (const float*)d_in[6];
    const float* values = (const float*)d_in[7];
    const float* noise  = (const float*)d_in[8];
    const int*   row    = (const int*)d_in[9];
    const int*   col    = (const int*)d_in[10];

    const int N = in_sizes[0] / D_DIM;
    const int E = in_sizes[7];
    float* out = (float*)d_out;

    char* ws = (char*)d_ws;
    ushort* Wt     = (ushort*)ws;                       // 131072 B (frag-major)
    float*  g_nb   = (float*)(ws + 131072);             // N
    float*  g_self = g_nb + N;                          // N
    float*  dis    = g_self + N;                        // N f32 (fallback) / bf16 alias
    ushort* disb   = (ushort*)dis;                      // Npad2 bf16 (lds path)
    ushort* priv   = (ushort*)(dis + N);                // NSL * NMAXL bf16 (~6.4MB)
    size_t pk_off  = 131072 + (size_t)3 * N * 4 + (size_t)NSL * NMAXL * 2;
    pk_off = (pk_off + 15) & ~(size_t)15;
    unsigned* pk   = (unsigned*)(ws + pk_off);          // E uints (~3.2MB)

    const int Npad2 = (N + 1) & ~1;
    int ES = ((E + NSL - 1) / NSL + 3) & ~3;            // edges/slice, mult of 4
    size_t need = pk_off + (size_t)E * 4;
    bool lds_path = (N <= NMAXL) && (need <= ws_size);

    int init_n = 2 * H_DIM * D_DIM;
    if (N > init_n) init_n = N;
    k0_init<<<(init_n + 255) / 256, 256, 0, stream>>>(W_nb, W_self, Wt, dis, N, lds_path ? 0 : 1);

    const int ntiles = (N + 63) / 64;
    k1_gemm<<<256, 512, 0, stream>>>(x, Wt, b_nb, b_self, W_att, g_nb, g_self, N, ntiles);

    if (lds_path) {
        int eb4 = ((E + 3) / 4 + 255) / 256;
        k2a_gate<<<eb4, 256, 0, stream>>>(row, col, values, noise, g_nb, g_self,
                                          b_att, pk, E);
        k2q_scatter<<<NSL * 4, 1024, 0, stream>>>(pk, priv, E, ES);
        k2c_reduce<<<((N + 1) / 2 + 255) / 256, 256, 0, stream>>>(priv, disb, N);
        int EB = ((E + 255) / 256 + 3) & ~3;            // edges/block, mult of 4
        k3_edge2_lds<<<256, 1024, 0, stream>>>(pk, col, out, disb, Npad2, E, EB);
    } else {
        k2_atomic_fb<<<(E + 255) / 256, 256, 0, stream>>>(row, col, values, noise,
                                                          g_nb, g_self, b_att, out, dis, E);
        k2c_rsqrt_fb<<<(N + 255) / 256, 256, 0, stream>>>(dis, N);
        k3_edge2_fb<<<(E + 255) / 256, 256, 0, stream>>>(row, col, out, dis, E);
    }
}